// Round 4
// baseline (3891.658 us; speedup 1.0000x reference)
//
#include <hip/hip_runtime.h>
#include <hip/hip_bf16.h>

// LSTM_66443144069713: 3-layer biLSTM, B=256 T=512 H=192 E=128, V=20000.
// Persistent per-layer kernel: WGs 0-31 run the full recurrence (W_hh in
// VGPRs/AGPRs, h in LDS, c in regs), WGs 32-255 produce gx chunks into a ring.
// Cross-XCD sync via agent-scope atomics (sc1, memory-side coherent; no L2
// flush/inv). fp16 MFMA, fp32 gate math.

typedef _Float16 f16;
typedef unsigned int u32;
typedef _Float16 f16x8 __attribute__((ext_vector_type(8)));
typedef float f32x4 __attribute__((ext_vector_type(4)));

#define ATL(p) __hip_atomic_load((p), __ATOMIC_RELAXED, __HIP_MEMORY_SCOPE_AGENT)
#define ATS(p, v) __hip_atomic_store((p), (v), __ATOMIC_RELAXED, __HIP_MEMORY_SCOPE_AGENT)

__device__ __forceinline__ float sigm(float x) {
  float e = __builtin_amdgcn_exp2f(x * -1.44269504088896f);
  return __builtin_amdgcn_rcpf(1.0f + e);
}
__device__ __forceinline__ float tanh_(float x) {
  float e = __builtin_amdgcn_exp2f(x * -2.88539008177793f);
  return __builtin_fmaf(2.0f, __builtin_amdgcn_rcpf(1.0f + e), -1.0f);
}

// ---------- small utility kernels ----------

__global__ void castk(const float* __restrict__ s, f16* __restrict__ d, int n) {
  int i = blockIdx.x * 256 + threadIdx.x;
  int st = gridDim.x * 256;
  for (; i < n; i += st) d[i] = (f16)s[i];
}

// W_hh (f32 [2][768][192]) -> f16 fragment layout [dir][w12][g][kk][lane][8]
__global__ void castwhh(const float* __restrict__ src, f16* __restrict__ dst) {
  int o = blockIdx.x * 256 + threadIdx.x;  // < 294912
  int e = o & 7, rest = o >> 3;
  int l = rest & 63; rest >>= 6;
  int kk = rest % 6; rest /= 6;
  int g = rest & 3; rest >>= 2;
  int w = rest % 12; int dir = rest / 12;
  int lo16 = l & 15, lhi = l >> 4;
  dst[o] = (f16)src[(size_t)(dir * 768 + g * 192 + w * 16 + lo16) * 192 + kk * 32 + lhi * 8 + e];
}

// A0[t*256+b][k] = fp16(emb[x[b][t]][k])
__global__ void embedk(const int* __restrict__ x, const float* __restrict__ emb,
                       f16* __restrict__ A0) {
  int row = blockIdx.x * 8 + (threadIdx.x >> 5);
  int t = row >> 8, b = row & 255;
  int xi = x[b * 512 + t];
  int c = (threadIdx.x & 31) * 4;
  float4 v = *(const float4*)(emb + (size_t)xi * 128 + c);
  union { f16 h[4]; uint2 u; } p;
  p.h[0] = (f16)v.x; p.h[1] = (f16)v.y; p.h[2] = (f16)v.z; p.h[3] = (f16)v.w;
  *(uint2*)(A0 + (size_t)row * 128 + c) = p.u;
}

__global__ void zerok(int* __restrict__ p) {
  if (threadIdx.x < 128) p[threadIdx.x] = 0;
}

// ---------- persistent per-layer kernel ----------
// gx dword index (within chunk): ((((dir*TC+tl)*16 + b16)*12 + w12)*512) + (g*2+qq)*64 + lane,
//   lane = ((b&15)>>2)*16 + (u&15); dword packs batch rows 2qq (lo), 2qq+1 (hi).
template <int KD>
__global__ __launch_bounds__(768)
void persistk(const f16* __restrict__ in, const f16* __restrict__ Bt,
              const float* __restrict__ bias, u32* gxring,
              const f16* __restrict__ whh16,
              f16* __restrict__ outh, float* __restrict__ hT,
              int* done, int* freed,
              int R, int NC, int TC, int wOut, int wHT) {
  union SMem {
    struct { uint4 A[1024]; uint4 B[1536]; } g;   // 16KB + 24KB
    f16 hb[2][16 * 200];                          // 12.8KB
  };
  __shared__ __align__(16) SMem sm;
  const int wg = blockIdx.x;
  const int tid = threadIdx.x;
  const int l = tid & 63, w = tid >> 6;
  const int lo16 = l & 15, lhi = l >> 4;
  const size_t chunkDw = (size_t)TC * 196608;  // dwords per gx chunk
  const int ntiles = 16 * TC;                  // done[] target per chunk

  if (wg < 32) {
    // ================= recurrence (full T, consuming chunks) =================
    const int dir = wg & 1, bblk = wg >> 1;
    const int u0 = w * 16;
    const int bb = bblk * 16 + lhi * 4;
    const int dc = dir * 192;

    f16x8 wf[4][6];
#pragma unroll
    for (int g = 0; g < 4; ++g)
#pragma unroll
      for (int kk = 0; kk < 6; ++kk)
        wf[g][kk] = *(const f16x8*)(whh16 + ((((size_t)dir * 12 + w) * 4 + g) * 6 + kk) * 512 + l * 8);

    {
      f16* hz = (f16*)sm.hb;
      for (int i = tid; i < 2 * 16 * 200; i += 768) hz[i] = (f16)0.f;
    }
    __syncthreads();
    float cq[4] = {0.f, 0.f, 0.f, 0.f};

    for (int c = 0; c < NC; ++c) {
      while (ATL(done + c) < ntiles) __builtin_amdgcn_s_sleep(8);
      u32* gxR = gxring + (size_t)(c % R) * chunkDw;
      u32 ga[8], gb[8];
      {
        const int tl0 = dir ? (TC - 1) : 0;
        size_t wb = ((((size_t)dir * TC + tl0) * 16 + bblk) * 12 + w) * 512;
#pragma unroll
        for (int k = 0; k < 8; ++k) ga[k] = ATL(gxR + wb + k * 64 + l);
      }
      const int tb0 = dir ? (511 - c * TC) : (c * TC);

#define RSTEP(S, CUR, NXT)                                                         \
  do {                                                                             \
    const int t = dir ? (tb0 - (S)) : (tb0 + (S));                                 \
    {                                                                              \
      int snx = ((S) + 1 < TC) ? (S) + 1 : (S);                                    \
      int tln = dir ? (TC - 1 - snx) : snx;                                        \
      size_t wb = ((((size_t)dir * TC + tln) * 16 + bblk) * 12 + w) * 512;         \
      _Pragma("unroll") for (int k = 0; k < 8; ++k) NXT[k] = ATL(gxR + wb + k * 64 + l); \
    }                                                                              \
    f32x4 ac[4] = {};                                                              \
    {                                                                              \
      const f16* hcur = sm.hb[(S) & 1];                                            \
      _Pragma("unroll") for (int kk = 0; kk < 6; ++kk) {                           \
        f16x8 av = *(const f16x8*)(hcur + lo16 * 200 + kk * 32 + lhi * 8);         \
        ac[0] = __builtin_amdgcn_mfma_f32_16x16x32_f16(av, wf[0][kk], ac[0], 0, 0, 0); \
        ac[1] = __builtin_amdgcn_mfma_f32_16x16x32_f16(av, wf[1][kk], ac[1], 0, 0, 0); \
        ac[2] = __builtin_amdgcn_mfma_f32_16x16x32_f16(av, wf[2][kk], ac[2], 0, 0, 0); \
        ac[3] = __builtin_amdgcn_mfma_f32_16x16x32_f16(av, wf[3][kk], ac[3], 0, 0, 0); \
      }                                                                            \
    }                                                                              \
    float z[4][4];                                                                 \
    _Pragma("unroll") for (int k = 0; k < 8; ++k) {                                \
      union { u32 u; f16 h[2]; } p;                                                \
      p.u = CUR[k];                                                                \
      const int g_ = k >> 1, qq_ = k & 1;                                          \
      z[g_][2 * qq_] = ac[g_][2 * qq_] + (float)p.h[0];                            \
      z[g_][2 * qq_ + 1] = ac[g_][2 * qq_ + 1] + (float)p.h[1];                    \
    }                                                                              \
    f16* hnew = sm.hb[((S) + 1) & 1];                                              \
    _Pragma("unroll") for (int q = 0; q < 4; ++q) {                                \
      float iv = sigm(z[0][q]), fv = sigm(z[1][q]);                                \
      float gv = tanh_(z[2][q]), ov = sigm(z[3][q]);                               \
      cq[q] = fv * cq[q] + iv * gv;                                                \
      float hv = ov * tanh_(cq[q]);                                                \
      f16 hh = (f16)hv;                                                            \
      hnew[(lhi * 4 + q) * 200 + u0 + lo16] = hh;                                  \
      if (wOut) outh[((size_t)t * 256 + bb + q) * 384 + dc + u0 + lo16] = hh;      \
      if (wHT && c == NC - 1 && (S) == TC - 1)                                     \
        hT[((size_t)dir * 256 + bb + q) * 192 + u0 + lo16] = hv;                   \
    }                                                                              \
    asm volatile("s_waitcnt lgkmcnt(0)" ::: "memory");                             \
    __builtin_amdgcn_s_barrier();                                                  \
    asm volatile("" ::: "memory");                                                 \
  } while (0)

      for (int s = 0; s < TC; s += 2) {
        RSTEP(s, ga, gb);
        RSTEP(s + 1, gb, ga);
      }
#undef RSTEP
      if (tid == 0)
        __hip_atomic_fetch_add(freed + c, 1, __ATOMIC_RELEASE, __HIP_MEMORY_SCOPE_AGENT);
    }
    return;
  }

  // ================= GEMM producer (all chunks, ring-buffered) =================
  const int gid = wg - 32;           // 0..223
  const int nblk = 4 * TC;           // (dir, 128-row tile) blocks per chunk
  const int wmm = w / 6, wn = w % 6; // 2x6 wave grid: 64 rows x 32 cols each
  constexpr int NKc = KD / 64;
  int kprev = -1;

  for (int gtb = gid; gtb < NC * nblk; gtb += 224) {
    const int k = gtb / nblk, blk = gtb % nblk;
    const int dir = blk / (2 * TC), r = blk % (2 * TC);
    if (k != kprev) {
      if (k >= R)
        while (ATL(freed + (k - R)) < 32) __builtin_amdgcn_s_sleep(8);
      kprev = k;
    }
    u32* gxW = gxring + (size_t)(k % R) * chunkDw;
    const int tbf = k * TC, tbb = 512 - (k + 1) * TC;
    const size_t ar0 = (size_t)(dir ? tbb : tbf) * 256 + r * 128;

    for (int g = 0; g < 4; ++g) {   // same A block 4x -> L2-hot for g>0
      const int btr0 = dir * 768 + g * 192;

      float bj[2];
#pragma unroll
      for (int j = 0; j < 2; ++j) bj[j] = bias[btr0 + wn * 32 + j * 16 + lo16];

      f32x4 acc[4][2] = {};
      uint4 a0, a1, b0, b1;

#define LDG(ko_)                                                                   \
  do {                                                                             \
    { int idx = tid; int row = idx >> 3, sl = idx & 7; int ch = sl ^ (row & 7);    \
      a0 = *(const uint4*)(in + (ar0 + row) * KD + (ko_)*64 + ch * 8); }           \
    if (tid < 256) { int idx = tid + 768; int row = idx >> 3, sl = idx & 7;        \
      int ch = sl ^ (row & 7);                                                     \
      a1 = *(const uint4*)(in + (ar0 + row) * KD + (ko_)*64 + ch * 8); }           \
    { int idx = tid; int row = idx >> 3, sl = idx & 7; int ch = sl ^ (row & 7);    \
      b0 = *(const uint4*)(Bt + (size_t)(btr0 + row) * KD + (ko_)*64 + ch * 8); }  \
    { int idx = tid + 768; int row = idx >> 3, sl = idx & 7; int ch = sl ^ (row & 7); \
      b1 = *(const uint4*)(Bt + (size_t)(btr0 + row) * KD + (ko_)*64 + ch * 8); }  \
  } while (0)

      LDG(0);
      for (int ko = 0; ko < NKc; ++ko) {
        __syncthreads();
        sm.g.A[tid] = a0;
        if (tid < 256) sm.g.A[tid + 768] = a1;
        sm.g.B[tid] = b0;
        sm.g.B[tid + 768] = b1;
        __syncthreads();
        if (ko + 1 < NKc) LDG(ko + 1);
#pragma unroll
        for (int kk = 0; kk < 2; ++kk) {
          f16x8 af[4], bf[2];
#pragma unroll
          for (int i = 0; i < 4; ++i) {
            int rowA = wmm * 64 + i * 16 + lo16;
            int slA = (kk * 4 + lhi) ^ (rowA & 7);
            af[i] = *(const f16x8*)((const char*)sm.g.A + rowA * 128 + slA * 16);
          }
#pragma unroll
          for (int j = 0; j < 2; ++j) {
            int colB = wn * 32 + j * 16 + lo16;
            int slB = (kk * 4 + lhi) ^ (colB & 7);
            bf[j] = *(const f16x8*)((const char*)sm.g.B + colB * 128 + slB * 16);
          }
#pragma unroll
          for (int i = 0; i < 4; ++i)
#pragma unroll
            for (int j = 0; j < 2; ++j)
              acc[i][j] = __builtin_amdgcn_mfma_f32_16x16x32_f16(af[i], bf[j], acc[i][j], 0, 0, 0);
        }
      }
#undef LDG

      // epilogue -> gx ring slot (agent-scope bypass stores)
#pragma unroll
      for (int i = 0; i < 4; ++i) {
        int rl = r * 128 + wmm * 64 + i * 16 + lhi * 4;
        int tl = rl >> 8;
        int b16 = (rl & 255) >> 4;
#pragma unroll
        for (int j = 0; j < 2; ++j) {
          int w12 = wn * 2 + j;
          size_t base = ((((size_t)dir * TC + tl) * 16 + b16) * 12 + w12) * 512;
#pragma unroll
          for (int qq = 0; qq < 2; ++qq) {
            union { f16 h[2]; u32 u; } p;
            p.h[0] = (f16)(acc[i][j][2 * qq] + bj[j]);
            p.h[1] = (f16)(acc[i][j][2 * qq + 1] + bj[j]);
            ATS(gxW + base + (g * 2 + qq) * 64 + l, p.u);
          }
        }
      }
      __syncthreads();  // protect LDS reuse across gate loop
    }
    __hip_atomic_fetch_add(done + k, 4, __ATOMIC_RELEASE, __HIP_MEMORY_SCOPE_AGENT);
  }
}

__global__ void fck(const float* __restrict__ hT, const float* __restrict__ w,
                    const float* __restrict__ fb, float* __restrict__ out) {
  int b = blockIdx.x * 64 + threadIdx.x;
  float a = fb[0];
#pragma unroll 4
  for (int u = 0; u < 192; ++u)
    a += w[u] * hT[(size_t)b * 192 + u] + w[192 + u] * hT[49152 + (size_t)b * 192 + u];
  out[b] = a;
}

extern "C" void kernel_launch(void* const* d_in, const int* in_sizes, int n_in,
                              void* d_out, int out_size, void* d_ws, size_t ws_size,
                              hipStream_t stream) {
  (void)in_sizes; (void)n_in; (void)out_size;
  const int* x = (const int*)d_in[0];
  const float* emb = (const float*)d_in[1];
  const float* Wih0 = (const float*)d_in[2];
  const float* Whh0 = (const float*)d_in[3];
  const float* b0 = (const float*)d_in[4];
  const float* Wihr = (const float*)d_in[5];
  const float* Whhr = (const float*)d_in[6];
  const float* br = (const float*)d_in[7];
  const float* fcw = (const float*)d_in[8];
  const float* fcb = (const float*)d_in[9];
  float* out = (float*)d_out;

  const size_t hB = 100663296ull;  // [512][256][384] f16
  const size_t fixedB = 2 * hB + 1179648ull + 589824ull + 393216ull + 4096ull;

  int TC = 8, R = 2;
  {
    const int cT[3] = {16, 8, 8};
    const int cR[3] = {2, 3, 2};
    for (int i = 0; i < 3; ++i) {
      size_t need = (size_t)cR[i] * cT[i] * 786432ull + fixedB;
      if (need <= ws_size) { TC = cT[i]; R = cR[i]; break; }
    }
  }
  const int NC = 512 / TC;

  char* ws = (char*)d_ws;
  u32* gx = (u32*)ws;
  size_t off = (size_t)R * TC * 786432ull;
  f16* h0 = (f16*)(ws + off); off += hB;
  f16* h1 = (f16*)(ws + off); off += hB;
  f16* A0 = h1;  // alias: A0 fully consumed by layer-0 gemm before layer-1 lstm writes h1
  f16* Bt = (f16*)(ws + off); off += 1179648ull;     // [1536][KD] f16 (per-layer)
  f16* whh16 = (f16*)(ws + off); off += 589824ull;   // fragment layout (per-layer)
  float* hT = (float*)(ws + off); off += 393216ull;  // [2][256][192] f32
  int* flags = (int*)(ws + off);                     // done[64] + freed[64]
  int* done = flags;
  int* freed = flags + 64;

  embedk<<<16384, 256, 0, stream>>>(x, emb, A0);

  for (int layer = 0; layer < 3; ++layer) {
    const int wOut = (layer < 2) ? 1 : 0;
    const int wHT = (layer == 2) ? 1 : 0;
    const float* bias = (layer == 0) ? b0 : (br + (layer - 1) * 1536);

    if (layer == 0) {
      castk<<<192, 256, 0, stream>>>(Wih0, Bt, 196608);
      castwhh<<<1152, 256, 0, stream>>>(Whh0, whh16);
    } else {
      castk<<<1152, 256, 0, stream>>>(Wihr + (size_t)(layer - 1) * 589824, Bt, 589824);
      castwhh<<<1152, 256, 0, stream>>>(Whhr + (size_t)(layer - 1) * 294912, whh16);
    }
    zerok<<<1, 128, 0, stream>>>(flags);

    if (layer == 0)
      persistk<128><<<256, 768, 0, stream>>>(A0, Bt, b0, gx, whh16, h0, hT,
                                             done, freed, R, NC, TC, wOut, wHT);
    else if (layer == 1)
      persistk<384><<<256, 768, 0, stream>>>(h0, Bt, bias, gx, whh16, h1, hT,
                                             done, freed, R, NC, TC, wOut, wHT);
    else
      persistk<384><<<256, 768, 0, stream>>>(h1, Bt, bias, gx, whh16, h0, hT,
                                             done, freed, R, NC, TC, wOut, wHT);
  }

  fck<<<4, 64, 0, stream>>>(hT, fcw, fcb, out);
}